// Round 1
// baseline (126.852 us; speedup 1.0000x reference)
//
#include <hip/hip_runtime.h>
#include <math.h>

#define TWO_PI_F 6.283185307179586f

// Kernel A: compute per-group rotation matrices R[G][9] (row-major, R[j][i])
// into workspace. R = I + sin(th)*K + (1-cos(th))*K^2, th = angle*2pi,
// K = skew(axis/|axis|). If apply_rand >= 0.5, R = I.
__global__ void compute_R_kernel(const float* __restrict__ axis,
                                 const float* __restrict__ angle,
                                 const float* __restrict__ apply_rand,
                                 float* __restrict__ R, int G) {
    int g = blockIdx.x * blockDim.x + threadIdx.x;
    if (g >= G) return;
    float a = axis[3 * g + 0];
    float b = axis[3 * g + 1];
    float c = axis[3 * g + 2];
    float inv = rsqrtf(a * a + b * b + c * c);
    a *= inv; b *= inv; c *= inv;
    float th = angle[g] * TWO_PI_F;
    float s, co;
    sincosf(th, &s, &co);
    float omc = 1.0f - co;

    float r00 = 1.0f - omc * (b * b + c * c);
    float r01 = -s * c + omc * (a * b);
    float r02 =  s * b + omc * (a * c);
    float r10 =  s * c + omc * (a * b);
    float r11 = 1.0f - omc * (a * a + c * c);
    float r12 = -s * a + omc * (b * c);
    float r20 = -s * b + omc * (a * c);
    float r21 =  s * a + omc * (b * c);
    float r22 = 1.0f - omc * (a * a + b * b);

    if (!(apply_rand[g] < 0.5f)) {
        r00 = 1.0f; r01 = 0.0f; r02 = 0.0f;
        r10 = 0.0f; r11 = 1.0f; r12 = 0.0f;
        r20 = 0.0f; r21 = 0.0f; r22 = 1.0f;
    }
    float* Rg = R + 9 * (size_t)g;
    Rg[0] = r00; Rg[1] = r01; Rg[2] = r02;
    Rg[3] = r10; Rg[4] = r11; Rg[5] = r12;
    Rg[6] = r20; Rg[7] = r21; Rg[8] = r22;
}

// Kernel B: out[n][j] = sum_i R[g(n)][j][i] * v[n][i].
// Each thread handles 4 rows = 12 floats = 3x float4 (48B, 16B-aligned).
template <bool HAS_BATCH>
__global__ void apply_rot_kernel(const float* __restrict__ v,
                                 const int* __restrict__ batch,
                                 const float* __restrict__ R,
                                 float* __restrict__ out, int n) {
    int nv4 = n >> 2;
    int stride = gridDim.x * blockDim.x;
    for (int t = blockIdx.x * blockDim.x + threadIdx.x; t < nv4; t += stride) {
        const float4* vin = reinterpret_cast<const float4*>(v + 12 * (size_t)t);
        float4 p0 = vin[0];
        float4 p1 = vin[1];
        float4 p2 = vin[2];
        float rows[4][3] = {
            {p0.x, p0.y, p0.z},
            {p0.w, p1.x, p1.y},
            {p1.z, p1.w, p2.x},
            {p2.y, p2.z, p2.w}};
        int gs[4];
        if (HAS_BATCH) {
            int4 bi = *reinterpret_cast<const int4*>(batch + 4 * (size_t)t);
            gs[0] = bi.x; gs[1] = bi.y; gs[2] = bi.z; gs[3] = bi.w;
        } else {
            int base = 4 * t;
            gs[0] = base; gs[1] = base + 1; gs[2] = base + 2; gs[3] = base + 3;
        }
        float o[12];
#pragma unroll
        for (int r = 0; r < 4; ++r) {
            const float* Rg = R + 9 * (size_t)gs[r];
            float v0 = rows[r][0], v1 = rows[r][1], v2 = rows[r][2];
            o[3 * r + 0] = Rg[0] * v0 + Rg[1] * v1 + Rg[2] * v2;
            o[3 * r + 1] = Rg[3] * v0 + Rg[4] * v1 + Rg[5] * v2;
            o[3 * r + 2] = Rg[6] * v0 + Rg[7] * v1 + Rg[8] * v2;
        }
        float4* vout = reinterpret_cast<float4*>(out + 12 * (size_t)t);
        vout[0] = make_float4(o[0], o[1], o[2], o[3]);
        vout[1] = make_float4(o[4], o[5], o[6], o[7]);
        vout[2] = make_float4(o[8], o[9], o[10], o[11]);
    }
    // Tail rows (n % 4) — handled scalar by a few threads of block 0.
    int tail = n & 3;
    if (tail && blockIdx.x == 0 && threadIdx.x < (unsigned)tail) {
        int row = (nv4 << 2) + (int)threadIdx.x;
        int g = HAS_BATCH ? batch[row] : row;
        const float* Rg = R + 9 * (size_t)g;
        float v0 = v[3 * (size_t)row + 0];
        float v1 = v[3 * (size_t)row + 1];
        float v2 = v[3 * (size_t)row + 2];
        out[3 * (size_t)row + 0] = Rg[0] * v0 + Rg[1] * v1 + Rg[2] * v2;
        out[3 * (size_t)row + 1] = Rg[3] * v0 + Rg[4] * v1 + Rg[5] * v2;
        out[3 * (size_t)row + 2] = Rg[6] * v0 + Rg[7] * v1 + Rg[8] * v2;
    }
}

static inline int grid_for(int nv4, int block, int cap) {
    int blocks = (nv4 + block - 1) / block;
    if (blocks < 1) blocks = 1;
    if (blocks > cap) blocks = cap;
    return blocks;
}

extern "C" void kernel_launch(void* const* d_in, const int* in_sizes, int n_in,
                              void* d_out, int out_size, void* d_ws, size_t ws_size,
                              hipStream_t stream) {
    const float* x          = (const float*)d_in[0];
    const float* edge_attr  = (const float*)d_in[1];
    const float* y          = (const float*)d_in[2];
    const int*   node_batch = (const int*)d_in[3];
    const int*   edge_batch = (const int*)d_in[4];
    const float* axis       = (const float*)d_in[5];
    const float* angle      = (const float*)d_in[6];
    const float* apply_rand = (const float*)d_in[7];

    const int N = in_sizes[3];      // node count
    const int E = in_sizes[4];      // edge count
    const int G = in_sizes[6];      // group count

    float* R = (float*)d_ws;        // G*9 floats = 288 KB
    float* x_out = (float*)d_out;
    float* e_out = x_out + 3 * (size_t)N;
    float* y_out = e_out + 3 * (size_t)E;

    const int BLOCK = 256;
    compute_R_kernel<<<(G + BLOCK - 1) / BLOCK, BLOCK, 0, stream>>>(
        axis, angle, apply_rand, R, G);

    apply_rot_kernel<true><<<grid_for(N >> 2, BLOCK, 2048), BLOCK, 0, stream>>>(
        x, node_batch, R, x_out, N);
    apply_rot_kernel<true><<<grid_for(E >> 2, BLOCK, 2048), BLOCK, 0, stream>>>(
        edge_attr, edge_batch, R, e_out, E);
    apply_rot_kernel<false><<<grid_for(G >> 2, BLOCK, 2048), BLOCK, 0, stream>>>(
        y, nullptr, R, y_out, G);
}

// Round 2
// 124.709 us; speedup vs baseline: 1.0172x; 1.0172x over previous
//
#include <hip/hip_runtime.h>
#include <math.h>

#define TWO_PI_F 6.283185307179586f

// Kernel A: compute per-group rotation matrices, PADDED to 12 floats/group
// (rows at offsets 0,4,8 => three aligned float4 loads downstream).
// R = I + sin(th)*K + (1-cos(th))*K^2, th = angle*2pi, K = skew(axis/|axis|).
// If apply_rand >= 0.5, R = I.
__global__ void compute_R_kernel(const float* __restrict__ axis,
                                 const float* __restrict__ angle,
                                 const float* __restrict__ apply_rand,
                                 float* __restrict__ R, int G) {
    int g = blockIdx.x * blockDim.x + threadIdx.x;
    if (g >= G) return;
    float a = axis[3 * g + 0];
    float b = axis[3 * g + 1];
    float c = axis[3 * g + 2];
    float inv = rsqrtf(a * a + b * b + c * c);
    a *= inv; b *= inv; c *= inv;
    float th = angle[g] * TWO_PI_F;
    float s, co;
    sincosf(th, &s, &co);
    float omc = 1.0f - co;

    float r00 = 1.0f - omc * (b * b + c * c);
    float r01 = -s * c + omc * (a * b);
    float r02 =  s * b + omc * (a * c);
    float r10 =  s * c + omc * (a * b);
    float r11 = 1.0f - omc * (a * a + c * c);
    float r12 = -s * a + omc * (b * c);
    float r20 = -s * b + omc * (a * c);
    float r21 =  s * a + omc * (b * c);
    float r22 = 1.0f - omc * (a * a + b * b);

    if (!(apply_rand[g] < 0.5f)) {
        r00 = 1.0f; r01 = 0.0f; r02 = 0.0f;
        r10 = 0.0f; r11 = 1.0f; r12 = 0.0f;
        r20 = 0.0f; r21 = 0.0f; r22 = 1.0f;
    }
    float4* Rg = reinterpret_cast<float4*>(R + 12 * (size_t)g);
    Rg[0] = make_float4(r00, r01, r02, 0.0f);
    Rg[1] = make_float4(r10, r11, r12, 0.0f);
    Rg[2] = make_float4(r20, r21, r22, 0.0f);
}

// Kernel B: out[n][j] = sum_i R[g(n)][j][i] * v[n][i].
// Each thread handles 4 rows = 12 floats = 3x float4 (48B, 16B-aligned).
// R gathers are 3x float4 per row (L1-broadcast: batch is sorted, lanes
// within a wave nearly always share g).
template <bool HAS_BATCH>
__global__ void apply_rot_kernel(const float* __restrict__ v,
                                 const int* __restrict__ batch,
                                 const float* __restrict__ R,
                                 float* __restrict__ out, int n) {
    int nv4 = n >> 2;
    int stride = gridDim.x * blockDim.x;
    for (int t = blockIdx.x * blockDim.x + threadIdx.x; t < nv4; t += stride) {
        const float4* vin = reinterpret_cast<const float4*>(v + 12 * (size_t)t);
        float4 p0 = vin[0];
        float4 p1 = vin[1];
        float4 p2 = vin[2];
        float rows[4][3] = {
            {p0.x, p0.y, p0.z},
            {p0.w, p1.x, p1.y},
            {p1.z, p1.w, p2.x},
            {p2.y, p2.z, p2.w}};
        int gs[4];
        if (HAS_BATCH) {
            int4 bi = *reinterpret_cast<const int4*>(batch + 4 * (size_t)t);
            gs[0] = bi.x; gs[1] = bi.y; gs[2] = bi.z; gs[3] = bi.w;
        } else {
            int base = 4 * t;
            gs[0] = base; gs[1] = base + 1; gs[2] = base + 2; gs[3] = base + 3;
        }
        float o[12];
#pragma unroll
        for (int r = 0; r < 4; ++r) {
            const float4* Rg = reinterpret_cast<const float4*>(R + 12 * (size_t)gs[r]);
            float4 R0 = Rg[0];
            float4 R1 = Rg[1];
            float4 R2 = Rg[2];
            float v0 = rows[r][0], v1 = rows[r][1], v2 = rows[r][2];
            o[3 * r + 0] = R0.x * v0 + R0.y * v1 + R0.z * v2;
            o[3 * r + 1] = R1.x * v0 + R1.y * v1 + R1.z * v2;
            o[3 * r + 2] = R2.x * v0 + R2.y * v1 + R2.z * v2;
        }
        float4* vout = reinterpret_cast<float4*>(out + 12 * (size_t)t);
        vout[0] = make_float4(o[0], o[1], o[2], o[3]);
        vout[1] = make_float4(o[4], o[5], o[6], o[7]);
        vout[2] = make_float4(o[8], o[9], o[10], o[11]);
    }
    // Tail rows (n % 4) — handled scalar by a few threads of block 0.
    int tail = n & 3;
    if (tail && blockIdx.x == 0 && threadIdx.x < (unsigned)tail) {
        int row = (nv4 << 2) + (int)threadIdx.x;
        int g = HAS_BATCH ? batch[row] : row;
        const float* Rg = R + 12 * (size_t)g;
        float v0 = v[3 * (size_t)row + 0];
        float v1 = v[3 * (size_t)row + 1];
        float v2 = v[3 * (size_t)row + 2];
        out[3 * (size_t)row + 0] = Rg[0] * v0 + Rg[1] * v1 + Rg[2]  * v2;
        out[3 * (size_t)row + 1] = Rg[4] * v0 + Rg[5] * v1 + Rg[6]  * v2;
        out[3 * (size_t)row + 2] = Rg[8] * v0 + Rg[9] * v1 + Rg[10] * v2;
    }
}

static inline int grid_for(int nv4, int block) {
    long long blocks = ((long long)nv4 + block - 1) / block;
    if (blocks < 1) blocks = 1;
    if (blocks > 65535) blocks = 65535;  // grid-stride loop covers the rest
    return (int)blocks;
}

extern "C" void kernel_launch(void* const* d_in, const int* in_sizes, int n_in,
                              void* d_out, int out_size, void* d_ws, size_t ws_size,
                              hipStream_t stream) {
    const float* x          = (const float*)d_in[0];
    const float* edge_attr  = (const float*)d_in[1];
    const float* y          = (const float*)d_in[2];
    const int*   node_batch = (const int*)d_in[3];
    const int*   edge_batch = (const int*)d_in[4];
    const float* axis       = (const float*)d_in[5];
    const float* angle      = (const float*)d_in[6];
    const float* apply_rand = (const float*)d_in[7];

    const int N = in_sizes[3];      // node count
    const int E = in_sizes[4];      // edge count
    const int G = in_sizes[6];      // group count

    float* R = (float*)d_ws;        // G*12 floats = 384 KB
    float* x_out = (float*)d_out;
    float* e_out = x_out + 3 * (size_t)N;
    float* y_out = e_out + 3 * (size_t)E;

    const int BLOCK = 256;
    compute_R_kernel<<<(G + BLOCK - 1) / BLOCK, BLOCK, 0, stream>>>(
        axis, angle, apply_rand, R, G);

    apply_rot_kernel<true><<<grid_for(N >> 2, BLOCK), BLOCK, 0, stream>>>(
        x, node_batch, R, x_out, N);
    apply_rot_kernel<true><<<grid_for(E >> 2, BLOCK), BLOCK, 0, stream>>>(
        edge_attr, edge_batch, R, e_out, E);
    apply_rot_kernel<false><<<grid_for(G >> 2, BLOCK), BLOCK, 0, stream>>>(
        y, nullptr, R, y_out, G);
}

// Round 3
// 112.414 us; speedup vs baseline: 1.1284x; 1.1094x over previous
//
#include <hip/hip_runtime.h>
#include <math.h>

#define TWO_PI_F 6.283185307179586f

// Kernel A: per-group rotation matrices, padded to 12 floats/group
// (rows at float4 offsets 0,1,2). R = I + sin*K + (1-cos)*K^2; identity if
// apply_rand >= 0.5.
__global__ void compute_R_kernel(const float* __restrict__ axis,
                                 const float* __restrict__ angle,
                                 const float* __restrict__ apply_rand,
                                 float* __restrict__ R, int G) {
    int g = blockIdx.x * blockDim.x + threadIdx.x;
    if (g >= G) return;
    float a = axis[3 * g + 0];
    float b = axis[3 * g + 1];
    float c = axis[3 * g + 2];
    float inv = rsqrtf(a * a + b * b + c * c);
    a *= inv; b *= inv; c *= inv;
    float th = angle[g] * TWO_PI_F;
    float s, co;
    sincosf(th, &s, &co);
    float omc = 1.0f - co;

    float r00 = 1.0f - omc * (b * b + c * c);
    float r01 = -s * c + omc * (a * b);
    float r02 =  s * b + omc * (a * c);
    float r10 =  s * c + omc * (a * b);
    float r11 = 1.0f - omc * (a * a + c * c);
    float r12 = -s * a + omc * (b * c);
    float r20 = -s * b + omc * (a * c);
    float r21 =  s * a + omc * (b * c);
    float r22 = 1.0f - omc * (a * a + b * b);

    if (!(apply_rand[g] < 0.5f)) {
        r00 = 1.0f; r01 = 0.0f; r02 = 0.0f;
        r10 = 0.0f; r11 = 1.0f; r12 = 0.0f;
        r20 = 0.0f; r21 = 0.0f; r22 = 1.0f;
    }
    float4* Rg = reinterpret_cast<float4*>(R + 12 * (size_t)g);
    Rg[0] = make_float4(r00, r01, r02, 0.0f);
    Rg[1] = make_float4(r10, r11, r12, 0.0f);
    Rg[2] = make_float4(r20, r21, r22, 0.0f);
}

// Kernel B (LDS-staged): block of 256 threads owns 1024 rows (3072 floats =
// 768 float4 = 48 KB). Global I/O is fully lane-contiguous float4; the
// stride-12-float AoS shuffle happens in LDS.
#define ROWS_PER_BLOCK 1024
#define F4_PER_BLOCK   768   // ROWS_PER_BLOCK*3/4

template <bool HAS_BATCH>
__global__ __launch_bounds__(256) void apply_rot_lds(
        const float* __restrict__ v,
        const int* __restrict__ batch,
        const float* __restrict__ R,
        float* __restrict__ out, int n) {
    __shared__ float buf[ROWS_PER_BLOCK * 3];
    float4* buf4 = reinterpret_cast<float4*>(buf);

    const int tid = threadIdx.x;
    const size_t rowBase = (size_t)blockIdx.x * ROWS_PER_BLOCK;
    int rowsHere = n - (int)rowBase;
    if (rowsHere > ROWS_PER_BLOCK) rowsHere = ROWS_PER_BLOCK;
    const int floatsHere = rowsHere * 3;
    const int f4Here = floatsHere >> 2;
    const int tailFloats = floatsHere & 3;

    // ---- Phase 1: coalesced global -> LDS ----
    const float4* vin4 = reinterpret_cast<const float4*>(v) + rowBase * 3 / 4;
    for (int i = tid; i < f4Here; i += 256) buf4[i] = vin4[i];
    if (tailFloats && tid < tailFloats) {
        int fi = (f4Here << 2) + tid;
        buf[fi] = v[rowBase * 3 + fi];
    }
    __syncthreads();

    // ---- Phase 2: rotate 4 rows per thread, in place ----
    const int nRow4 = rowsHere >> 2;
    if (tid < nRow4) {
        float4 p0 = buf4[3 * tid + 0];
        float4 p1 = buf4[3 * tid + 1];
        float4 p2 = buf4[3 * tid + 2];
        float rows[4][3] = {
            {p0.x, p0.y, p0.z},
            {p0.w, p1.x, p1.y},
            {p1.z, p1.w, p2.x},
            {p2.y, p2.z, p2.w}};
        int gs[4];
        if (HAS_BATCH) {
            int4 bi = *reinterpret_cast<const int4*>(batch + rowBase + 4 * (size_t)tid);
            gs[0] = bi.x; gs[1] = bi.y; gs[2] = bi.z; gs[3] = bi.w;
        } else {
            int base = (int)rowBase + 4 * tid;
            gs[0] = base; gs[1] = base + 1; gs[2] = base + 2; gs[3] = base + 3;
        }
        float o[12];
#pragma unroll
        for (int r = 0; r < 4; ++r) {
            const float4* Rg = reinterpret_cast<const float4*>(R + 12 * (size_t)gs[r]);
            float4 R0 = Rg[0];
            float4 R1 = Rg[1];
            float4 R2 = Rg[2];
            float v0 = rows[r][0], v1 = rows[r][1], v2 = rows[r][2];
            o[3 * r + 0] = R0.x * v0 + R0.y * v1 + R0.z * v2;
            o[3 * r + 1] = R1.x * v0 + R1.y * v1 + R1.z * v2;
            o[3 * r + 2] = R2.x * v0 + R2.y * v1 + R2.z * v2;
        }
        buf4[3 * tid + 0] = make_float4(o[0], o[1], o[2], o[3]);
        buf4[3 * tid + 1] = make_float4(o[4], o[5], o[6], o[7]);
        buf4[3 * tid + 2] = make_float4(o[8], o[9], o[10], o[11]);
    } else if (tid == nRow4 && (rowsHere & 3)) {
        // scalar tail rows (n % 4) — absent for these input sizes, kept for safety
        for (int r = nRow4 * 4; r < rowsHere; ++r) {
            size_t row = rowBase + r;
            int g = HAS_BATCH ? batch[row] : (int)row;
            const float* Rg = R + 12 * (size_t)g;
            float v0 = buf[3 * r + 0], v1 = buf[3 * r + 1], v2 = buf[3 * r + 2];
            float t0 = Rg[0] * v0 + Rg[1] * v1 + Rg[2]  * v2;
            float t1 = Rg[4] * v0 + Rg[5] * v1 + Rg[6]  * v2;
            float t2 = Rg[8] * v0 + Rg[9] * v1 + Rg[10] * v2;
            buf[3 * r + 0] = t0; buf[3 * r + 1] = t1; buf[3 * r + 2] = t2;
        }
    }
    __syncthreads();

    // ---- Phase 3: coalesced LDS -> global ----
    float4* vout4 = reinterpret_cast<float4*>(out) + rowBase * 3 / 4;
    for (int i = tid; i < f4Here; i += 256) vout4[i] = buf4[i];
    if (tailFloats && tid < tailFloats) {
        int fi = (f4Here << 2) + tid;
        out[rowBase * 3 + fi] = buf[fi];
    }
}

extern "C" void kernel_launch(void* const* d_in, const int* in_sizes, int n_in,
                              void* d_out, int out_size, void* d_ws, size_t ws_size,
                              hipStream_t stream) {
    const float* x          = (const float*)d_in[0];
    const float* edge_attr  = (const float*)d_in[1];
    const float* y          = (const float*)d_in[2];
    const int*   node_batch = (const int*)d_in[3];
    const int*   edge_batch = (const int*)d_in[4];
    const float* axis       = (const float*)d_in[5];
    const float* angle      = (const float*)d_in[6];
    const float* apply_rand = (const float*)d_in[7];

    const int N = in_sizes[3];      // node count
    const int E = in_sizes[4];      // edge count
    const int G = in_sizes[6];      // group count

    float* R = (float*)d_ws;        // G*12 floats = 384 KB
    float* x_out = (float*)d_out;
    float* e_out = x_out + 3 * (size_t)N;
    float* y_out = e_out + 3 * (size_t)E;

    const int BLOCK = 256;
    compute_R_kernel<<<(G + BLOCK - 1) / BLOCK, BLOCK, 0, stream>>>(
        axis, angle, apply_rand, R, G);

    int nbN = (N + ROWS_PER_BLOCK - 1) / ROWS_PER_BLOCK;
    int nbE = (E + ROWS_PER_BLOCK - 1) / ROWS_PER_BLOCK;
    int nbG = (G + ROWS_PER_BLOCK - 1) / ROWS_PER_BLOCK;

    apply_rot_lds<true><<<nbN, BLOCK, 0, stream>>>(x, node_batch, R, x_out, N);
    apply_rot_lds<true><<<nbE, BLOCK, 0, stream>>>(edge_attr, edge_batch, R, e_out, E);
    apply_rot_lds<false><<<nbG, BLOCK, 0, stream>>>(y, nullptr, R, y_out, G);
}